// Round 2
// 388.829 us; speedup vs baseline: 1.0044x; 1.0044x over previous
//
#include <hip/hip_runtime.h>

// Problem constants (from reference):
//   B=64, C=256, H=W=56 -> HW=3136 (=784 float4), SQ=64
//   x: [B,C,H,W] f32; w1: [SQ,C]; b1: [SQ]; w2: [C,SQ]; b2: [C]
#define SE_B   64
#define SE_C   256
#define SE_SQ  64
#define SE_HW  3136
#define SE_HW4 784            // float4s per plane
#define PPB    16             // planes per block
#define NBLK   (SE_B * SE_C / PPB)   // 1024 blocks

// Native vector type for nontemporal builtins (HIP_vector_type is rejected).
typedef float vfloat4 __attribute__((ext_vector_type(4)));

// ---------------------------------------------------------------------------
// Kernel 1: global average pool. 1024 blocks x 16 contiguous planes each.
// Per-plane summation order identical to the verified baseline (thread t
// reads float4 t, t+256, t+512, t+768) -> bitwise-same pool numerics.
// Normal (caching) loads on purpose: this pass parks x in L3 for kernel 2.
// ---------------------------------------------------------------------------
__global__ __launch_bounds__(256) void se_pool(const float* __restrict__ x,
                                               float* __restrict__ s) {
    const int plane0 = blockIdx.x * PPB;
    const float4* xp = (const float4*)x + (size_t)plane0 * SE_HW4;
    const int lane = threadIdx.x & 63;
    const int wave = threadIdx.x >> 6;

    __shared__ float red[PPB][4];

    #pragma unroll
    for (int p = 0; p < PPB; ++p) {
        const float4* pp = xp + p * SE_HW4;
        float a = 0.0f;
        #pragma unroll
        for (int k = 0; k < 3; ++k) {
            float4 v = pp[threadIdx.x + k * 256];
            a += (v.x + v.y) + (v.z + v.w);
        }
        if (threadIdx.x < (SE_HW4 - 3 * 256)) {   // 784 = 3*256 + 16
            float4 v = pp[threadIdx.x + 768];
            a += (v.x + v.y) + (v.z + v.w);
        }
        #pragma unroll
        for (int off = 32; off > 0; off >>= 1)
            a += __shfl_down(a, off, 64);
        if (lane == 0) red[p][wave] = a;
    }
    __syncthreads();
    if (threadIdx.x < PPB) {
        float t = (red[threadIdx.x][0] + red[threadIdx.x][1]) +
                  (red[threadIdx.x][2] + red[threadIdx.x][3]);
        s[plane0 + threadIdx.x] = t * (1.0f / (float)SE_HW);
    }
}

// ---------------------------------------------------------------------------
// Kernel 2: fused excitation MLP + broadcast scale.
// Each block owns 16 contiguous planes (one batch b, 16 channels c0..c0+15).
// It redundantly computes h = relu(w1 @ s_b + b1) (16K FMA, trivial) and the
// 16 gate values it needs, keeping g entirely in LDS (no global round trip).
// Scale pass: x read is the LAST use (nontemporal load, should be L3 hits
// from kernel 1); out is write-once (nontemporal store, does not evict x).
// ---------------------------------------------------------------------------
__global__ __launch_bounds__(256) void se_fc_scale(const float* __restrict__ x,
                                                   const float* __restrict__ s,
                                                   const float* __restrict__ w1,
                                                   const float* __restrict__ b1,
                                                   const float* __restrict__ w2,
                                                   const float* __restrict__ b2,
                                                   float* __restrict__ out) {
    const int tid    = threadIdx.x;
    const int plane0 = blockIdx.x * PPB;
    const int b      = plane0 >> 8;    // /256 channels
    const int c0     = plane0 & 255;

    __shared__ float s_sh[SE_C];
    __shared__ float h_sh[SE_SQ];
    __shared__ float g_sh[PPB];

    s_sh[tid] = s[b * SE_C + tid];
    __syncthreads();

    // h = relu(w1 @ s_b + b1), threads 0..63, 4-way split accumulators for ILP
    if (tid < SE_SQ) {
        const float* w = w1 + (size_t)tid * SE_C;
        float a0 = b1[tid], a1 = 0.0f, a2 = 0.0f, a3 = 0.0f;
        #pragma unroll 8
        for (int c = 0; c < SE_C; c += 4) {
            a0 = fmaf(w[c],     s_sh[c],     a0);
            a1 = fmaf(w[c + 1], s_sh[c + 1], a1);
            a2 = fmaf(w[c + 2], s_sh[c + 2], a2);
            a3 = fmaf(w[c + 3], s_sh[c + 3], a3);
        }
        h_sh[tid] = fmaxf((a0 + a1) + (a2 + a3), 0.0f);
    }
    __syncthreads();

    // g_c = sigmoid(w2[c,:] @ h + b2[c]) for this block's 16 channels
    if (tid < PPB) {
        const int c = c0 + tid;
        const float* w = w2 + (size_t)c * SE_SQ;
        float a0 = b2[c], a1 = 0.0f, a2 = 0.0f, a3 = 0.0f;
        #pragma unroll
        for (int k = 0; k < SE_SQ; k += 4) {
            a0 = fmaf(w[k],     h_sh[k],     a0);
            a1 = fmaf(w[k + 1], h_sh[k + 1], a1);
            a2 = fmaf(w[k + 2], h_sh[k + 2], a2);
            a3 = fmaf(w[k + 3], h_sh[k + 3], a3);
        }
        float z = (a0 + a1) + (a2 + a3);
        g_sh[tid] = 1.0f / (1.0f + __expf(-z));
    }
    __syncthreads();

    // Scale 16 contiguous planes = 12544 float4 (49 iters * 256 threads, exact)
    const vfloat4* xp = (const vfloat4*)x + (size_t)plane0 * SE_HW4;
    vfloat4*       op = (vfloat4*)out + (size_t)plane0 * SE_HW4;
    #pragma unroll 7
    for (int k = 0; k < 49; ++k) {
        const int j = tid + k * 256;
        const float gv = g_sh[j / SE_HW4];     // magic-mul div by 784
        vfloat4 v = __builtin_nontemporal_load(xp + j);
        v *= gv;
        __builtin_nontemporal_store(v, op + j);
    }
}

extern "C" void kernel_launch(void* const* d_in, const int* in_sizes, int n_in,
                              void* d_out, int out_size, void* d_ws, size_t ws_size,
                              hipStream_t stream) {
    const float* x  = (const float*)d_in[0];
    const float* w1 = (const float*)d_in[1];
    const float* b1 = (const float*)d_in[2];
    const float* w2 = (const float*)d_in[3];
    const float* b2 = (const float*)d_in[4];
    float* out = (float*)d_out;

    // workspace: s[B*C] only (64 KB); fully overwritten before read, poison-safe
    float* s = (float*)d_ws;

    se_pool    <<<NBLK, 256, 0, stream>>>(x, s);
    se_fc_scale<<<NBLK, 256, 0, stream>>>(x, s, w1, b1, w2, b2, out);
}